// Round 5
// baseline (117.979 us; speedup 1.0000x reference)
//
#include <hip/hip_runtime.h>
#include <math.h>

#define TPB 256
#define CH  64

typedef float f4v __attribute__((ext_vector_type(4)));

// ---------------------------------------------------------------------------
// Prep: meta[i] = { |xobs_i|^2 / ls^2, alpha0[i], alpha1[i], 0 }
// ---------------------------------------------------------------------------
__global__ __launch_bounds__(256) void prep_meta(
    const float* __restrict__ xobs, const float* __restrict__ alpha0,
    const float* __restrict__ alpha1, const float* __restrict__ rawls,
    float4* __restrict__ meta, int n_obs)
{
    const int i = blockIdx.x * 256 + threadIdx.x;
    if (i >= n_obs) return;
    const float r  = rawls[0];
    const float ls = fmaxf(r, 0.f) + log1pf(__expf(-fabsf(r)));
    const float inv_ls2 = 1.f / (ls * ls);
    const float* rp = xobs + (size_t)i * 16;
    float s = 0.f;
    #pragma unroll
    for (int k = 0; k < 16; ++k) s = fmaf(rp[k], rp[k], s);
    meta[i] = make_float4(s * inv_ls2, alpha0[i], alpha1[i], 0.f);
}

// ---------------------------------------------------------------------------
// Main: thread = one column j. Rows are wave-uniform -> scalar (SGPR) loads,
// no LDS at all. sq = (|xo|^2 + |x|^2 - 2 dot) / ls^2 with 1/ls^2 folded in.
// ---------------------------------------------------------------------------
__global__ __launch_bounds__(TPB, 8) void matern_partial(
    const float* __restrict__ xobs, const float* __restrict__ x,
    const float4* __restrict__ meta,
    const float* __restrict__ tfl, const float* __restrict__ rawls,
    const int* __restrict__ rngo, const int* __restrict__ rngx,
    float* __restrict__ f01, int n_obs, int n_x)
{
    const int tid = threadIdx.x;
    const int j   = blockIdx.x * TPB + tid;
    const int c0  = blockIdx.y * CH;
    const int c1  = min(c0 + CH, n_obs);

    const float r  = rawls[0];
    const float ls = fmaxf(r, 0.f) + log1pf(__expf(-fabsf(r)));
    const float inv_ls2 = 1.f / (ls * ls);
    const float c2 = -2.f * inv_ls2;

    // per-thread column (raw values; scaling folded into sq)
    const bool active = (j < n_x);
    const int  jj     = active ? j : 0;
    float xj[16];
    float nx = 0.f;
    #pragma unroll
    for (int k = 0; k < 16; ++k) {
        const float v = x[(size_t)jj * 16 + k];
        xj[k] = v;
        nx = fmaf(v, v, nx);
    }
    nx *= inv_ls2;

    // transfer-factor row for this column's domain
    const float t0 = 1.f / (1.f + __expf(-tfl[0]));   // F[0][1]
    const float t1 = 1.f / (1.f + __expf(-tfl[1]));   // F[0][2]
    const float t2 = 1.f / (1.f + __expf(-tfl[2]));   // F[1][2]
    const int dxj = (jj >= rngx[2] ? 1 : 0) + (jj >= rngx[4] ? 1 : 0);
    const float fd0 = (dxj == 0) ? 1.f : ((dxj == 1) ? t0 : t1);
    const float fd1 = (dxj == 0) ? t0  : ((dxj == 1) ? 1.f : t2);
    const float fd2 = (dxj == 0) ? t1  : ((dxj == 1) ? t2  : 1.f);

    const float S5  = 2.2360679774997896f;     // sqrt(5)
    const float C53 = 5.0f / 3.0f;
    const float CE  = -3.2259641988921336f;    // -sqrt(5)*log2(e)

    float acc0 = 0.f, acc1 = 0.f;

    #pragma unroll
    for (int dom = 0; dom < 3; ++dom) {
        const int ds = max(c0, rngo[dom * 2 + 0]);
        const int de = min(c1, rngo[dom * 2 + 1]);
        float s0 = 0.f, s1 = 0.f;
        #pragma unroll 4
        for (int i = ds; i < de; ++i) {
            // wave-uniform row -> scalar loads (SGPRs), no LDS
            const f4v* rp = (const f4v*)(xobs + (size_t)i * 16);
            const f4v A = rp[0], B = rp[1], C = rp[2], D = rp[3];
            const float4 mt = meta[i];

            // two 8-deep fmac chains, SGPR src0 + resident VGPR xj
            float q0 = A.x * xj[0];
            q0 = fmaf(A.y, xj[1], q0); q0 = fmaf(A.z, xj[2], q0); q0 = fmaf(A.w, xj[3], q0);
            q0 = fmaf(B.x, xj[4], q0); q0 = fmaf(B.y, xj[5], q0); q0 = fmaf(B.z, xj[6], q0);
            q0 = fmaf(B.w, xj[7], q0);
            float q1 = C.x * xj[8];
            q1 = fmaf(C.y, xj[9],  q1); q1 = fmaf(C.z, xj[10], q1); q1 = fmaf(C.w, xj[11], q1);
            q1 = fmaf(D.x, xj[12], q1); q1 = fmaf(D.y, xj[13], q1); q1 = fmaf(D.z, xj[14], q1);
            q1 = fmaf(D.w, xj[15], q1);
            const float dot = q0 + q1;

            float sq = fmaf(c2, dot, mt.x + nx);
            sq = fmaxf(sq, 1e-12f);
            const float rs   = __frsqrt_rn(sq);
            const float d    = sq * rs;                        // sqrt(sq)
            const float s5d  = S5 * d;
            const float poly = fmaf(C53, sq, 1.0f + s5d);
            const float e    = __builtin_amdgcn_exp2f(CE * d); // exp(-sqrt5*d), 1x v_exp_f32
            const float m    = poly * e;
            s0 = fmaf(mt.y, m, s0);
            s1 = fmaf(mt.z, m, s1);
        }
        const float fd = (dom == 0) ? fd0 : ((dom == 1) ? fd1 : fd2);
        acc0 = fmaf(fd, s0, acc0);
        acc1 = fmaf(fd, s1, acc1);
    }

    if (active) {
        atomicAdd(&f01[j], acc0);
        atomicAdd(&f01[n_x + j], acc1);
    }
}

// ---------------------------------------------------------------------------
// out[j] = w[j]*f0[j] + (1-w[j])*f1[j]
// ---------------------------------------------------------------------------
__global__ void combine_out(const float* __restrict__ w,
                            const float* __restrict__ f01,
                            float* __restrict__ out, int n_x)
{
    const int j = blockIdx.x * 256 + threadIdx.x;
    if (j < n_x) {
        const float wv = w[j];
        out[j] = wv * f01[j] + (1.f - wv) * f01[n_x + j];
    }
}

extern "C" void kernel_launch(void* const* d_in, const int* in_sizes, int n_in,
                              void* d_out, int out_size, void* d_ws, size_t ws_size,
                              hipStream_t stream)
{
    const float* xobs = (const float*)d_in[0];
    const float* x    = (const float*)d_in[1];
    const float* w    = (const float*)d_in[2];
    const float* a0   = (const float*)d_in[3];
    const float* a1   = (const float*)d_in[4];
    const float* tfl  = (const float*)d_in[5];
    const float* rls  = (const float*)d_in[6];
    const int*   rngo = (const int*)d_in[7];
    const int*   rngx = (const int*)d_in[8];

    const int n_obs = in_sizes[0] / 16;
    const int n_x   = in_sizes[1] / 16;

    float*  f01  = (float*)d_ws;                                   // [2][n_x]
    float4* meta = (float4*)((char*)d_ws + sizeof(float) * 2 * (size_t)n_x);

    (void)hipMemsetAsync(f01, 0, sizeof(float) * 2 * (size_t)n_x, stream);
    prep_meta<<<(n_obs + 255) / 256, 256, 0, stream>>>(xobs, a0, a1, rls, meta, n_obs);

    dim3 grid((n_x + TPB - 1) / TPB, (n_obs + CH - 1) / CH);
    matern_partial<<<grid, TPB, 0, stream>>>(xobs, x, meta, tfl, rls,
                                             rngo, rngx, f01, n_obs, n_x);

    combine_out<<<(n_x + 255) / 256, 256, 0, stream>>>(w, f01, (float*)d_out, n_x);
}

// Round 7
// 101.907 us; speedup vs baseline: 1.1577x; 1.1577x over previous
//
#include <hip/hip_runtime.h>
#include <math.h>

typedef _Float16 f16x8 __attribute__((ext_vector_type(8)));
typedef float    f32x4 __attribute__((ext_vector_type(4)));

// ---------------------------------------------------------------------------
// Prep: f16 hi/lo split of xobs (A side, K-packed [hi16|lo16]) and x (B side,
// separate hi/lo arrays), plus scaled norms. ls = softplus(raw).
// ---------------------------------------------------------------------------
__global__ __launch_bounds__(256) void prep_split(
    const float* __restrict__ xobs, const float* __restrict__ x,
    const float* __restrict__ rawls,
    _Float16* __restrict__ ap,   // [n_obs][32] = [hi(16) | lo(16)]
    _Float16* __restrict__ bh,   // [n_x][16]
    _Float16* __restrict__ bl,   // [n_x][16]
    float* __restrict__ no2, float* __restrict__ nx2,
    int n_obs, int n_x)
{
    const int i = blockIdx.x * 256 + threadIdx.x;
    const float r  = rawls[0];
    const float ls = fmaxf(r, 0.f) + log1pf(__expf(-fabsf(r)));
    const float inv_ls2 = 1.f / (ls * ls);

    if (i < n_obs) {
        float s = 0.f;
        #pragma unroll
        for (int k = 0; k < 16; ++k) {
            const float v = xobs[(size_t)i * 16 + k];
            s = fmaf(v, v, s);
            const _Float16 h = (_Float16)v;
            ap[(size_t)i * 32 + k]      = h;
            ap[(size_t)i * 32 + 16 + k] = (_Float16)(v - (float)h);
        }
        no2[i] = s * inv_ls2;
    }
    if (i < n_x) {
        float s = 0.f;
        #pragma unroll
        for (int k = 0; k < 16; ++k) {
            const float v = x[(size_t)i * 16 + k];
            s = fmaf(v, v, s);
            const _Float16 h = (_Float16)v;
            bh[(size_t)i * 16 + k] = h;
            bl[(size_t)i * 16 + k] = (_Float16)(v - (float)h);
        }
        nx2[i] = s * inv_ls2;
    }
}

// ---------------------------------------------------------------------------
// Main: attention-style. Wave = one 16-col j-tile; loop over 16-row i-tiles.
// dot via 2x mfma_f32_16x16x32_f16 (split-f16: hh + lh + hl), Matern tail on
// VALU (4 pairs/lane), fd wave-uniform per i-tile (boundaries 16-aligned).
// No LDS, no barriers; operands stream from L2-hot prep arrays.
// ---------------------------------------------------------------------------
__global__ __launch_bounds__(256, 4) void matern_mfma(
    const _Float16* __restrict__ ap, const _Float16* __restrict__ bh,
    const _Float16* __restrict__ bl,
    const float* __restrict__ no2, const float* __restrict__ nx2,
    const float* __restrict__ alpha0, const float* __restrict__ alpha1,
    const float* __restrict__ tfl, const float* __restrict__ rawls,
    const int* __restrict__ rngo, const int* __restrict__ rngx,
    float* __restrict__ f01, int n_obs, int n_x, int ntiles_i, int tiles_per_chunk)
{
    const int wave = threadIdx.x >> 6;
    const int lane = threadIdx.x & 63;
    const int njt  = n_x >> 4;                  // 375
    const int jt   = blockIdx.x * 4 + wave;
    if (jt >= njt) return;
    const int g16 = lane >> 4;                  // 0..3 (K-group / C-row-group)
    const int l16 = lane & 15;                  // col within tile
    const int j   = jt * 16 + l16;

    // B fragments, hoisted for the whole kernel.
    // B[k][col]: lane needs k = g16*8 + r. B1 = [hb|hb] (K=32), B2 = [lb|0].
    const f16x8 B1 = *(const f16x8*)(bh + (size_t)j * 16 + (g16 & 1) * 8);
    f16x8 B2 = f16x8{0, 0, 0, 0, 0, 0, 0, 0};
    if (g16 < 2) B2 = *(const f16x8*)(bl + (size_t)j * 16 + g16 * 8);

    const float r  = rawls[0];
    const float ls = fmaxf(r, 0.f) + log1pf(__expf(-fabsf(r)));
    const float inv_ls2 = 1.f / (ls * ls);
    const float c2  = -2.f * inv_ls2;
    const float nxj = nx2[j];

    const float t0 = 1.f / (1.f + __expf(-tfl[0]));
    const float t1 = 1.f / (1.f + __expf(-tfl[1]));
    const float t2 = 1.f / (1.f + __expf(-tfl[2]));
    const int dxj = (j >= rngx[2] ? 1 : 0) + (j >= rngx[4] ? 1 : 0);
    const float fdr0 = (dxj == 0) ? 1.f : ((dxj == 1) ? t0 : t1);
    const float fdr1 = (dxj == 0) ? t0  : ((dxj == 1) ? 1.f : t2);
    const float fdr2 = (dxj == 0) ? t1  : ((dxj == 1) ? t2  : 1.f);

    const float S5   = 2.2360679774997896f;    // sqrt(5)
    const float C53  = 5.0f / 3.0f;
    const float NL2E = -1.4426950408889634f;   // -log2(e)

    float s0 = 0.f, s1 = 0.f;
    const int it0 = blockIdx.y * tiles_per_chunk;
    const int it1 = min(it0 + tiles_per_chunk, ntiles_i);

    for (int it = it0; it < it1; ++it) {
        const int ibase = it * 16;
        // A[row][k]: lane holds row = l16, k = g16*8 + r  (ap is K-packed)
        const f16x8 A1 = *(const f16x8*)(ap + (size_t)(ibase + l16) * 32 + g16 * 8);
        f32x4 acc = {0.f, 0.f, 0.f, 0.f};
        acc = __builtin_amdgcn_mfma_f32_16x16x32_f16(A1, B1, acc, 0, 0, 0);  // hh + lh
        acc = __builtin_amdgcn_mfma_f32_16x16x32_f16(A1, B2, acc, 0, 0, 0);  // + hl

        // meta for this lane's 4 C-rows: rows = ibase + g16*4 + rr
        const int rbase = ibase + g16 * 4;
        const f32x4 nov = *(const f32x4*)(no2   + rbase);
        const f32x4 a0v = *(const f32x4*)(alpha0 + rbase);
        const f32x4 a1v = *(const f32x4*)(alpha1 + rbase);

        const int domi = (ibase >= rngo[2] ? 1 : 0) + (ibase >= rngo[4] ? 1 : 0);
        const float fd = (domi == 0) ? fdr0 : ((domi == 1) ? fdr1 : fdr2);

        #pragma unroll
        for (int rr = 0; rr < 4; ++rr) {
            float sq = fmaf(c2, acc[rr], nov[rr] + nxj);
            sq = fmaxf(sq, 1e-12f);
            const float rs   = __frsqrt_rn(sq);
            const float dd   = sq * rs;                       // sqrt(sq)
            const float s5d  = S5 * dd;
            const float poly = fmaf(C53, sq, 1.f + s5d);
            const float e    = __builtin_amdgcn_exp2f(NL2E * s5d);
            const float m    = poly * e;
            s0 = fmaf(fd * a0v[rr], m, s0);
            s1 = fmaf(fd * a1v[rr], m, s1);
        }
    }

    // lanes (l16, l16+16, l16+32, l16+48) hold partials for the same j
    s0 += __shfl_xor(s0, 16, 64);
    s0 += __shfl_xor(s0, 32, 64);
    s1 += __shfl_xor(s1, 16, 64);
    s1 += __shfl_xor(s1, 32, 64);
    if (g16 == 0) {
        atomicAdd(&f01[j], s0);
        atomicAdd(&f01[n_x + j], s1);
    }
}

// ---------------------------------------------------------------------------
// out[j] = w[j]*f0[j] + (1-w[j])*f1[j]
// ---------------------------------------------------------------------------
__global__ void combine_out(const float* __restrict__ w,
                            const float* __restrict__ f01,
                            float* __restrict__ out, int n_x)
{
    const int j = blockIdx.x * 256 + threadIdx.x;
    if (j < n_x) {
        const float wv = w[j];
        out[j] = wv * f01[j] + (1.f - wv) * f01[n_x + j];
    }
}

extern "C" void kernel_launch(void* const* d_in, const int* in_sizes, int n_in,
                              void* d_out, int out_size, void* d_ws, size_t ws_size,
                              hipStream_t stream)
{
    const float* xobs = (const float*)d_in[0];
    const float* x    = (const float*)d_in[1];
    const float* w    = (const float*)d_in[2];
    const float* a0   = (const float*)d_in[3];
    const float* a1   = (const float*)d_in[4];
    const float* tfl  = (const float*)d_in[5];
    const float* rls  = (const float*)d_in[6];
    const int*   rngo = (const int*)d_in[7];
    const int*   rngx = (const int*)d_in[8];

    const int n_obs = in_sizes[0] / 16;
    const int n_x   = in_sizes[1] / 16;

    // workspace layout (256B-aligned chunks)
    char* p = (char*)d_ws;
    auto take = [&](size_t bytes) { char* q = p; p += (bytes + 255) & ~(size_t)255; return q; };
    float*     f01 = (float*)    take(sizeof(float) * 2 * (size_t)n_x);
    _Float16*  ap  = (_Float16*) take(sizeof(_Float16) * 32 * (size_t)n_obs);
    _Float16*  bh  = (_Float16*) take(sizeof(_Float16) * 16 * (size_t)n_x);
    _Float16*  bl  = (_Float16*) take(sizeof(_Float16) * 16 * (size_t)n_x);
    float*     no2 = (float*)    take(sizeof(float) * (size_t)n_obs);
    float*     nx2 = (float*)    take(sizeof(float) * (size_t)n_x);

    (void)hipMemsetAsync(f01, 0, sizeof(float) * 2 * (size_t)n_x, stream);

    const int nmax = (n_obs > n_x) ? n_obs : n_x;
    prep_split<<<(nmax + 255) / 256, 256, 0, stream>>>(xobs, x, rls, ap, bh, bl,
                                                       no2, nx2, n_obs, n_x);

    const int njt = n_x / 16;            // 375 (n_x divisible by 16)
    const int ntiles_i = n_obs / 16;     // 375
    const int tiles_per_chunk = 15;
    const int gy = (ntiles_i + tiles_per_chunk - 1) / tiles_per_chunk;   // 25
    dim3 grid((njt + 3) / 4, gy);
    matern_mfma<<<grid, 256, 0, stream>>>(ap, bh, bl, no2, nx2, a0, a1, tfl, rls,
                                          rngo, rngx, f01, n_obs, n_x,
                                          ntiles_i, tiles_per_chunk);

    combine_out<<<(n_x + 255) / 256, 256, 0, stream>>>(w, f01, (float*)d_out, n_x);
}

// Round 8
// 101.594 us; speedup vs baseline: 1.1613x; 1.0031x over previous
//
#include <hip/hip_runtime.h>
#include <math.h>

typedef _Float16 f16x8 __attribute__((ext_vector_type(8)));
typedef float    f32x4 __attribute__((ext_vector_type(4)));

// ---------------------------------------------------------------------------
// Prep: f16 hi/lo split of xobs (A side, K-packed [hi16|lo16]) and x (B side),
// 5x-scaled norms (u = 5*sq fold), and transfer-factor-prefolded alphas:
// a0f[d][i] = alpha0[i] * F[dom_i][d]  (d = x-column domain), likewise a1f.
// ---------------------------------------------------------------------------
__global__ __launch_bounds__(256) void prep_split(
    const float* __restrict__ xobs, const float* __restrict__ x,
    const float* __restrict__ alpha0, const float* __restrict__ alpha1,
    const float* __restrict__ tfl, const float* __restrict__ rawls,
    const int* __restrict__ rngo,
    _Float16* __restrict__ ap,   // [n_obs][32] = [hi(16) | lo(16)]
    _Float16* __restrict__ bh,   // [n_x][16]
    _Float16* __restrict__ bl,   // [n_x][16]
    float* __restrict__ no5, float* __restrict__ nx5,
    float* __restrict__ a0f, float* __restrict__ a1f,   // [3][n_obs]
    int n_obs, int n_x)
{
    const int i = blockIdx.x * 256 + threadIdx.x;
    const float r  = rawls[0];
    const float ls = fmaxf(r, 0.f) + log1pf(__expf(-fabsf(r)));
    const float s5_ls2 = 5.f / (ls * ls);

    if (i < n_obs) {
        float s = 0.f;
        #pragma unroll
        for (int k = 0; k < 16; ++k) {
            const float v = xobs[(size_t)i * 16 + k];
            s = fmaf(v, v, s);
            const _Float16 h = (_Float16)v;
            ap[(size_t)i * 32 + k]      = h;
            ap[(size_t)i * 32 + 16 + k] = (_Float16)(v - (float)h);
        }
        no5[i] = s * s5_ls2;

        const float t0 = 1.f / (1.f + __expf(-tfl[0]));
        const float t1 = 1.f / (1.f + __expf(-tfl[1]));
        const float t2 = 1.f / (1.f + __expf(-tfl[2]));
        const int dom = (i >= rngo[2] ? 1 : 0) + (i >= rngo[4] ? 1 : 0);
        // F rows: [1,t0,t1] / [t0,1,t2] / [t1,t2,1]
        const float F0 = (dom == 0) ? 1.f : ((dom == 1) ? t0 : t1);
        const float F1 = (dom == 0) ? t0  : ((dom == 1) ? 1.f : t2);
        const float F2 = (dom == 0) ? t1  : ((dom == 1) ? t2  : 1.f);
        const float av0 = alpha0[i], av1 = alpha1[i];
        a0f[i]              = av0 * F0;
        a0f[n_obs + i]      = av0 * F1;
        a0f[2 * n_obs + i]  = av0 * F2;
        a1f[i]              = av1 * F0;
        a1f[n_obs + i]      = av1 * F1;
        a1f[2 * n_obs + i]  = av1 * F2;
    }
    if (i < n_x) {
        float s = 0.f;
        #pragma unroll
        for (int k = 0; k < 16; ++k) {
            const float v = x[(size_t)i * 16 + k];
            s = fmaf(v, v, s);
            const _Float16 h = (_Float16)v;
            bh[(size_t)i * 16 + k] = h;
            bl[(size_t)i * 16 + k] = (_Float16)(v - (float)h);
        }
        nx5[i] = s * s5_ls2;
    }
}

// ---------------------------------------------------------------------------
// Main: wave = one 16-col j-tile; 2 i-tiles per iteration (ILP). Dot via
// 2x mfma_f32_16x16x32_f16 per tile (split-f16 hh+lh+hl). Tail on VALU with
// u = 5*sq: s5d = sqrt(u), poly = 1 + s5d + u/3, m = poly*exp2(-log2e*s5d).
// Transfer factor prefolded into a0f/a1f. No LDS, no barriers.
// ---------------------------------------------------------------------------
__global__ __launch_bounds__(256, 4) void matern_mfma(
    const _Float16* __restrict__ ap, const _Float16* __restrict__ bh,
    const _Float16* __restrict__ bl,
    const float* __restrict__ no5, const float* __restrict__ nx5,
    const float* __restrict__ a0f, const float* __restrict__ a1f,
    const float* __restrict__ rawls, const int* __restrict__ rngx,
    float* __restrict__ f01, int n_obs, int n_x, int ntiles_i, int tiles_per_chunk)
{
    const int wave = threadIdx.x >> 6;
    const int lane = threadIdx.x & 63;
    const int njt  = n_x >> 4;
    const int jt   = blockIdx.x * 4 + wave;
    if (jt >= njt) return;
    const int g16 = lane >> 4;
    const int l16 = lane & 15;
    const int j   = jt * 16 + l16;

    // B fragments (whole kernel). B[k][col]: lane needs k = g16*8 + r.
    const f16x8 B1 = *(const f16x8*)(bh + (size_t)j * 16 + (g16 & 1) * 8);
    f16x8 B2 = f16x8{0, 0, 0, 0, 0, 0, 0, 0};
    if (g16 < 2) B2 = *(const f16x8*)(bl + (size_t)j * 16 + g16 * 8);

    const float r  = rawls[0];
    const float ls = fmaxf(r, 0.f) + log1pf(__expf(-fabsf(r)));
    const float c2_5 = -10.f / (ls * ls);
    const float nx5j = nx5[j];

    // domain of this j-tile (boundaries 16-aligned -> wave-uniform)
    const int dxj = (j >= rngx[2] ? 1 : 0) + (j >= rngx[4] ? 1 : 0);
    const float* __restrict__ a0p = a0f + (size_t)dxj * n_obs;
    const float* __restrict__ a1p = a1f + (size_t)dxj * n_obs;

    const float C13  = 1.f / 3.f;
    const float NL2E = -1.4426950408889634f;   // -log2(e)

    float s0 = 0.f, s1 = 0.f;
    const int it0 = blockIdx.y * tiles_per_chunk;
    const int it1 = min(it0 + tiles_per_chunk, ntiles_i);

    #define TAIL4(ACC, NOV, A0V, A1V)                                        \
        _Pragma("unroll")                                                    \
        for (int rr = 0; rr < 4; ++rr) {                                     \
            float u = fmaf(c2_5, (ACC)[rr], (NOV)[rr] + nx5j);               \
            u = fmaxf(u, 1e-11f);                                            \
            const float rs   = __frsqrt_rn(u);                               \
            const float s5d  = u * rs;                      /* sqrt(u) */    \
            const float poly = fmaf(C13, u, 1.f + s5d);                      \
            const float e    = __builtin_amdgcn_exp2f(NL2E * s5d);           \
            const float m    = poly * e;                                     \
            s0 = fmaf((A0V)[rr], m, s0);                                     \
            s1 = fmaf((A1V)[rr], m, s1);                                     \
        }

    int it = it0;
    for (; it + 1 < it1; it += 2) {
        const int ia = it * 16, ib = ia + 16;
        // independent loads first (ILP across both tiles)
        const f16x8 Aa = *(const f16x8*)(ap + (size_t)(ia + l16) * 32 + g16 * 8);
        const f16x8 Ab = *(const f16x8*)(ap + (size_t)(ib + l16) * 32 + g16 * 8);
        const int ra = ia + g16 * 4, rb = ib + g16 * 4;
        const f32x4 nova = *(const f32x4*)(no5 + ra);
        const f32x4 novb = *(const f32x4*)(no5 + rb);
        const f32x4 a0a  = *(const f32x4*)(a0p + ra);
        const f32x4 a0b  = *(const f32x4*)(a0p + rb);
        const f32x4 a1a  = *(const f32x4*)(a1p + ra);
        const f32x4 a1b  = *(const f32x4*)(a1p + rb);

        f32x4 acca = {0.f, 0.f, 0.f, 0.f};
        acca = __builtin_amdgcn_mfma_f32_16x16x32_f16(Aa, B1, acca, 0, 0, 0);
        acca = __builtin_amdgcn_mfma_f32_16x16x32_f16(Aa, B2, acca, 0, 0, 0);
        f32x4 accb = {0.f, 0.f, 0.f, 0.f};
        accb = __builtin_amdgcn_mfma_f32_16x16x32_f16(Ab, B1, accb, 0, 0, 0);
        accb = __builtin_amdgcn_mfma_f32_16x16x32_f16(Ab, B2, accb, 0, 0, 0);

        TAIL4(acca, nova, a0a, a1a)
        TAIL4(accb, novb, a0b, a1b)
    }
    if (it < it1) {
        const int ia = it * 16;
        const f16x8 Aa = *(const f16x8*)(ap + (size_t)(ia + l16) * 32 + g16 * 8);
        const int ra = ia + g16 * 4;
        const f32x4 nova = *(const f32x4*)(no5 + ra);
        const f32x4 a0a  = *(const f32x4*)(a0p + ra);
        const f32x4 a1a  = *(const f32x4*)(a1p + ra);
        f32x4 acca = {0.f, 0.f, 0.f, 0.f};
        acca = __builtin_amdgcn_mfma_f32_16x16x32_f16(Aa, B1, acca, 0, 0, 0);
        acca = __builtin_amdgcn_mfma_f32_16x16x32_f16(Aa, B2, acca, 0, 0, 0);
        TAIL4(acca, nova, a0a, a1a)
    }
    #undef TAIL4

    // lanes (l16, +16, +32, +48) hold partials for the same j
    s0 += __shfl_xor(s0, 16, 64);
    s0 += __shfl_xor(s0, 32, 64);
    s1 += __shfl_xor(s1, 16, 64);
    s1 += __shfl_xor(s1, 32, 64);
    if (g16 == 0) {
        atomicAdd(&f01[j], s0);
        atomicAdd(&f01[n_x + j], s1);
    }
}

// ---------------------------------------------------------------------------
// out[j] = w[j]*f0[j] + (1-w[j])*f1[j]
// ---------------------------------------------------------------------------
__global__ void combine_out(const float* __restrict__ w,
                            const float* __restrict__ f01,
                            float* __restrict__ out, int n_x)
{
    const int j = blockIdx.x * 256 + threadIdx.x;
    if (j < n_x) {
        const float wv = w[j];
        out[j] = wv * f01[j] + (1.f - wv) * f01[n_x + j];
    }
}

extern "C" void kernel_launch(void* const* d_in, const int* in_sizes, int n_in,
                              void* d_out, int out_size, void* d_ws, size_t ws_size,
                              hipStream_t stream)
{
    const float* xobs = (const float*)d_in[0];
    const float* x    = (const float*)d_in[1];
    const float* w    = (const float*)d_in[2];
    const float* a0   = (const float*)d_in[3];
    const float* a1   = (const float*)d_in[4];
    const float* tfl  = (const float*)d_in[5];
    const float* rls  = (const float*)d_in[6];
    const int*   rngo = (const int*)d_in[7];
    const int*   rngx = (const int*)d_in[8];

    const int n_obs = in_sizes[0] / 16;
    const int n_x   = in_sizes[1] / 16;

    char* p = (char*)d_ws;
    auto take = [&](size_t bytes) { char* q = p; p += (bytes + 255) & ~(size_t)255; return q; };
    float*     f01 = (float*)    take(sizeof(float) * 2 * (size_t)n_x);
    _Float16*  ap  = (_Float16*) take(sizeof(_Float16) * 32 * (size_t)n_obs);
    _Float16*  bh  = (_Float16*) take(sizeof(_Float16) * 16 * (size_t)n_x);
    _Float16*  bl  = (_Float16*) take(sizeof(_Float16) * 16 * (size_t)n_x);
    float*     no5 = (float*)    take(sizeof(float) * (size_t)n_obs);
    float*     nx5 = (float*)    take(sizeof(float) * (size_t)n_x);
    float*     a0f = (float*)    take(sizeof(float) * 3 * (size_t)n_obs);
    float*     a1f = (float*)    take(sizeof(float) * 3 * (size_t)n_obs);

    (void)hipMemsetAsync(f01, 0, sizeof(float) * 2 * (size_t)n_x, stream);

    const int nmax = (n_obs > n_x) ? n_obs : n_x;
    prep_split<<<(nmax + 255) / 256, 256, 0, stream>>>(
        xobs, x, a0, a1, tfl, rls, rngo, ap, bh, bl, no5, nx5, a0f, a1f, n_obs, n_x);

    const int njt = n_x / 16;            // 375
    const int ntiles_i = n_obs / 16;     // 375
    const int tiles_per_chunk = 15;
    const int gy = (ntiles_i + tiles_per_chunk - 1) / tiles_per_chunk;   // 25
    dim3 grid((njt + 3) / 4, gy);
    matern_mfma<<<grid, 256, 0, stream>>>(ap, bh, bl, no5, nx5, a0f, a1f, rls,
                                          rngx, f01, n_obs, n_x,
                                          ntiles_i, tiles_per_chunk);

    combine_out<<<(n_x + 255) / 256, 256, 0, stream>>>(w, f01, (float*)d_out, n_x);
}

// Round 9
// 99.931 us; speedup vs baseline: 1.1806x; 1.0166x over previous
//
#include <hip/hip_runtime.h>
#include <math.h>

typedef _Float16 f16x8 __attribute__((ext_vector_type(8)));
typedef float    f32x4 __attribute__((ext_vector_type(4)));

// ---------------------------------------------------------------------------
// Fused prep, fully parallel: 16 lanes per row, 16 rows per block.
//  - f16 hi/lo split of xobs -> ap [n_obs][32] = [hi16|lo16] (K-packed)
//    and x -> bh/bl [n_x][16]
//  - 5x-scaled norms no5/nx5 (u = 5*sq fold)
//  - transfer-factor-prefolded alphas a0f/a1f [3][n_obs] (lane k==1)
// ---------------------------------------------------------------------------
__global__ __launch_bounds__(256) void prep_all(
    const float* __restrict__ xobs, const float* __restrict__ x,
    const float* __restrict__ alpha0, const float* __restrict__ alpha1,
    const float* __restrict__ tfl, const float* __restrict__ rawls,
    const int* __restrict__ rngo,
    _Float16* __restrict__ ap, _Float16* __restrict__ bh, _Float16* __restrict__ bl,
    float* __restrict__ no5, float* __restrict__ nx5,
    float* __restrict__ a0f, float* __restrict__ a1f,
    int n_obs, int n_x)
{
    const int t   = threadIdx.x;
    const int r   = t >> 4;
    const int k   = t & 15;
    const int row = blockIdx.x * 16 + r;

    const float rv = rawls[0];
    const float ls = fmaxf(rv, 0.f) + log1pf(__expf(-fabsf(rv)));
    const float s5_ls2 = 5.f / (ls * ls);

    if (row < n_obs) {
        const float v = xobs[(size_t)row * 16 + k];
        float nv = v * v;
        nv += __shfl_xor(nv, 1, 64);
        nv += __shfl_xor(nv, 2, 64);
        nv += __shfl_xor(nv, 4, 64);
        nv += __shfl_xor(nv, 8, 64);
        const _Float16 h = (_Float16)v;
        ap[(size_t)row * 32 + k]      = h;
        ap[(size_t)row * 32 + 16 + k] = (_Float16)(v - (float)h);
        if (k == 0) no5[row] = nv * s5_ls2;
        if (k == 1) {
            const float t0 = 1.f / (1.f + __expf(-tfl[0]));
            const float t1 = 1.f / (1.f + __expf(-tfl[1]));
            const float t2 = 1.f / (1.f + __expf(-tfl[2]));
            const int dom = (row >= rngo[2] ? 1 : 0) + (row >= rngo[4] ? 1 : 0);
            // F rows: [1,t0,t1] / [t0,1,t2] / [t1,t2,1]
            const float F0 = (dom == 0) ? 1.f : ((dom == 1) ? t0 : t1);
            const float F1 = (dom == 0) ? t0  : ((dom == 1) ? 1.f : t2);
            const float F2 = (dom == 0) ? t1  : ((dom == 1) ? t2  : 1.f);
            const float av0 = alpha0[row], av1 = alpha1[row];
            a0f[row]             = av0 * F0;
            a0f[n_obs + row]     = av0 * F1;
            a0f[2 * n_obs + row] = av0 * F2;
            a1f[row]             = av1 * F0;
            a1f[n_obs + row]     = av1 * F1;
            a1f[2 * n_obs + row] = av1 * F2;
        }
    }
    if (row < n_x) {
        const float v = x[(size_t)row * 16 + k];
        float nv = v * v;
        nv += __shfl_xor(nv, 1, 64);
        nv += __shfl_xor(nv, 2, 64);
        nv += __shfl_xor(nv, 4, 64);
        nv += __shfl_xor(nv, 8, 64);
        const _Float16 h = (_Float16)v;
        bh[(size_t)row * 16 + k] = h;
        bl[(size_t)row * 16 + k] = (_Float16)(v - (float)h);
        if (k == 0) nx5[row] = nv * s5_ls2;
    }
}

// ---------------------------------------------------------------------------
// Main: wave = one 16-col j-tile; one i-tile per iteration; 8 waves/SIMD for
// TLP (ILP-2 measured as zero gain). Dot via 2x mfma_f32_16x16x32_f16
// (split-f16 hh+lh+hl). Tail with u = 5*sq: s5d = sqrt(u),
// poly = 1 + s5d + u/3, m = poly * exp2(-log2e * s5d).
// Transfer factor prefolded into a0f/a1f. No LDS, no barriers.
// ---------------------------------------------------------------------------
__global__ __launch_bounds__(256, 8) void matern_mfma(
    const _Float16* __restrict__ ap, const _Float16* __restrict__ bh,
    const _Float16* __restrict__ bl,
    const float* __restrict__ no5, const float* __restrict__ nx5,
    const float* __restrict__ a0f, const float* __restrict__ a1f,
    const float* __restrict__ rawls, const int* __restrict__ rngx,
    float* __restrict__ f01, int n_obs, int n_x, int ntiles_i, int tiles_per_chunk)
{
    const int wave = threadIdx.x >> 6;
    const int lane = threadIdx.x & 63;
    const int njt  = n_x >> 4;
    const int jt   = blockIdx.x * 4 + wave;
    if (jt >= njt) return;
    const int g16 = lane >> 4;
    const int l16 = lane & 15;
    const int j   = jt * 16 + l16;

    // B fragments (whole kernel). B[k][col]: lane needs k = g16*8 + r.
    const f16x8 B1 = *(const f16x8*)(bh + (size_t)j * 16 + (g16 & 1) * 8);
    f16x8 B2 = f16x8{0, 0, 0, 0, 0, 0, 0, 0};
    if (g16 < 2) B2 = *(const f16x8*)(bl + (size_t)j * 16 + g16 * 8);

    const float rv = rawls[0];
    const float ls = fmaxf(rv, 0.f) + log1pf(__expf(-fabsf(rv)));
    const float c2_5 = -10.f / (ls * ls);
    const float nx5j = nx5[j];

    // domain of this j-tile (boundaries 16-aligned -> wave-uniform)
    const int dxj = (j >= rngx[2] ? 1 : 0) + (j >= rngx[4] ? 1 : 0);
    const float* __restrict__ a0p = a0f + (size_t)dxj * n_obs;
    const float* __restrict__ a1p = a1f + (size_t)dxj * n_obs;

    const float C13  = 1.f / 3.f;
    const float NL2E = -1.4426950408889634f;   // -log2(e)

    float s0 = 0.f, s1 = 0.f;
    const int it0 = blockIdx.y * tiles_per_chunk;
    const int it1 = min(it0 + tiles_per_chunk, ntiles_i);

    for (int it = it0; it < it1; ++it) {
        const int ia = it * 16;
        const f16x8 Aa = *(const f16x8*)(ap + (size_t)(ia + l16) * 32 + g16 * 8);
        const int ra = ia + g16 * 4;
        const f32x4 nov = *(const f32x4*)(no5 + ra);
        const f32x4 a0v = *(const f32x4*)(a0p + ra);
        const f32x4 a1v = *(const f32x4*)(a1p + ra);

        f32x4 acc = {0.f, 0.f, 0.f, 0.f};
        acc = __builtin_amdgcn_mfma_f32_16x16x32_f16(Aa, B1, acc, 0, 0, 0);
        acc = __builtin_amdgcn_mfma_f32_16x16x32_f16(Aa, B2, acc, 0, 0, 0);

        #pragma unroll
        for (int rr = 0; rr < 4; ++rr) {
            float u = fmaf(c2_5, acc[rr], nov[rr] + nx5j);
            u = fmaxf(u, 1e-11f);
            const float rs   = __frsqrt_rn(u);
            const float s5d  = u * rs;                    // sqrt(u)
            const float poly = fmaf(C13, u, 1.f + s5d);
            const float e    = __builtin_amdgcn_exp2f(NL2E * s5d);
            const float m    = poly * e;
            s0 = fmaf(a0v[rr], m, s0);
            s1 = fmaf(a1v[rr], m, s1);
        }
    }

    // lanes (l16, +16, +32, +48) hold partials for the same j
    s0 += __shfl_xor(s0, 16, 64);
    s0 += __shfl_xor(s0, 32, 64);
    s1 += __shfl_xor(s1, 16, 64);
    s1 += __shfl_xor(s1, 32, 64);
    if (g16 == 0) {
        atomicAdd(&f01[j], s0);
        atomicAdd(&f01[n_x + j], s1);
    }
}

// ---------------------------------------------------------------------------
// out[j] = w[j]*f0[j] + (1-w[j])*f1[j]
// ---------------------------------------------------------------------------
__global__ void combine_out(const float* __restrict__ w,
                            const float* __restrict__ f01,
                            float* __restrict__ out, int n_x)
{
    const int j = blockIdx.x * 256 + threadIdx.x;
    if (j < n_x) {
        const float wv = w[j];
        out[j] = wv * f01[j] + (1.f - wv) * f01[n_x + j];
    }
}

extern "C" void kernel_launch(void* const* d_in, const int* in_sizes, int n_in,
                              void* d_out, int out_size, void* d_ws, size_t ws_size,
                              hipStream_t stream)
{
    const float* xobs = (const float*)d_in[0];
    const float* x    = (const float*)d_in[1];
    const float* w    = (const float*)d_in[2];
    const float* a0   = (const float*)d_in[3];
    const float* a1   = (const float*)d_in[4];
    const float* tfl  = (const float*)d_in[5];
    const float* rls  = (const float*)d_in[6];
    const int*   rngo = (const int*)d_in[7];
    const int*   rngx = (const int*)d_in[8];

    const int n_obs = in_sizes[0] / 16;
    const int n_x   = in_sizes[1] / 16;

    char* p = (char*)d_ws;
    auto take = [&](size_t bytes) { char* q = p; p += (bytes + 255) & ~(size_t)255; return q; };
    float*     f01 = (float*)    take(sizeof(float) * 2 * (size_t)n_x);
    _Float16*  ap  = (_Float16*) take(sizeof(_Float16) * 32 * (size_t)n_obs);
    _Float16*  bh  = (_Float16*) take(sizeof(_Float16) * 16 * (size_t)n_x);
    _Float16*  bl  = (_Float16*) take(sizeof(_Float16) * 16 * (size_t)n_x);
    float*     no5 = (float*)    take(sizeof(float) * (size_t)n_obs);
    float*     nx5 = (float*)    take(sizeof(float) * (size_t)n_x);
    float*     a0f = (float*)    take(sizeof(float) * 3 * (size_t)n_obs);
    float*     a1f = (float*)    take(sizeof(float) * 3 * (size_t)n_obs);

    (void)hipMemsetAsync(f01, 0, sizeof(float) * 2 * (size_t)n_x, stream);

    const int nmax = (n_obs > n_x) ? n_obs : n_x;
    prep_all<<<(nmax + 15) / 16, 256, 0, stream>>>(
        xobs, x, a0, a1, tfl, rls, rngo, ap, bh, bl, no5, nx5, a0f, a1f, n_obs, n_x);

    const int njt = n_x / 16;            // 375
    const int ntiles_i = n_obs / 16;     // 375
    const int tiles_per_chunk = 15;
    const int gy = (ntiles_i + tiles_per_chunk - 1) / tiles_per_chunk;   // 25
    dim3 grid((njt + 3) / 4, gy);
    matern_mfma<<<grid, 256, 0, stream>>>(ap, bh, bl, no5, nx5, a0f, a1f, rls,
                                          rngx, f01, n_obs, n_x,
                                          ntiles_i, tiles_per_chunk);

    combine_out<<<(n_x + 255) / 256, 256, 0, stream>>>(w, f01, (float*)d_out, n_x);
}